// Round 1
// baseline (2718.364 us; speedup 1.0000x reference)
//
#include <hip/hip_runtime.h>
#include <cstdint>
#include <cstddef>

#define N_POINTS 32768
#define KDEG 16
#define N_EDGES (N_POINTS*KDEG)
#define BATCH 2
#define HID 64
#define LIFTD 256
#define PROJD 256
#define KIN 68
#define NLAYERS 4

#define DSTS 16          // dst nodes per block (exclusively owned -> no global atomics)
#define LK_THREADS 128   // 2 waves
#define LK_WAVES 2
#define GSTRIDE 66       // LDS row stride (floats): even (float2-aligned), 2-way bank alias = free

__device__ __forceinline__ float gelu_f(float x) {
    return 0.5f * x * (1.0f + erff(x * 0.70710678118654752440f));
}

// ---------------- CSR build ----------------
__global__ void hist_kernel(const int* __restrict__ ei, int* __restrict__ counts) {
    int e = blockIdx.x * 256 + threadIdx.x;
    if (e < N_EDGES) atomicAdd(&counts[ei[N_EDGES + e]], 1);
}

__global__ void scan_kernel(const int* __restrict__ counts, int* __restrict__ row_start) {
    __shared__ int sums[1024];
    const int tid = threadIdx.x;
    const int base = tid * 32;
    int s = 0;
    for (int i = 0; i < 32; ++i) s += counts[base + i];
    sums[tid] = s;
    __syncthreads();
    const int own = s;
    for (int off = 1; off < 1024; off <<= 1) {
        int v = (tid >= off) ? sums[tid - off] : 0;
        __syncthreads();
        sums[tid] += v;
        __syncthreads();
    }
    int run = sums[tid] - own;   // exclusive prefix
    for (int i = 0; i < 32; ++i) { row_start[base + i] = run; run += counts[base + i]; }
    if (tid == 1023) row_start[N_POINTS] = N_EDGES;
}

__global__ void fill_kernel(const int* __restrict__ ei, const int* __restrict__ row_start,
                            int* __restrict__ cursor, int* __restrict__ csr_src,
                            int* __restrict__ csr_dst) {
    int e = blockIdx.x * 256 + threadIdx.x;
    if (e < N_EDGES) {
        int s = ei[e], d = ei[N_EDGES + e];
        int p = atomicAdd(&cursor[d], 1);
        int idx = row_start[d] + p;
        csr_src[idx] = s;
        csr_dst[idx] = d;
    }
}

// ---------------- lift: h = gelu([x,pos]@W1+b1)@W2+b2 ----------------
__global__ __launch_bounds__(256) void lift_kernel(
    const float* __restrict__ x, const float* __restrict__ pos,
    const float* __restrict__ w1, const float* __restrict__ b1,
    const float* __restrict__ w2, const float* __restrict__ b2,
    float* __restrict__ h)
{
    const int gid = blockIdx.x * 256 + threadIdx.x;   // 0..B*N-1 (= b*N + i)
    const int i = gid & (N_POINTS - 1);
    const float x0 = x[(size_t)gid * 3 + 0];
    const float x1 = x[(size_t)gid * 3 + 1];
    const float x2 = x[(size_t)gid * 3 + 2];
    const float2 p = *(const float2*)(pos + 2 * i);

    float acc[64];
#pragma unroll
    for (int c = 0; c < 64; ++c) acc[c] = b2[c];

    for (int j = 0; j < LIFTD; ++j) {
        float tv = b1[j] + x0 * w1[j] + x1 * w1[LIFTD + j] + x2 * w1[2 * LIFTD + j]
                 + p.x * w1[3 * LIFTD + j] + p.y * w1[4 * LIFTD + j];
        const float g = gelu_f(tv);
        const float* __restrict__ wp = w2 + j * 64;
#pragma unroll
        for (int c = 0; c < 64; ++c) acc[c] += g * wp[c];
    }
    float4* ho = (float4*)(h + (size_t)gid * 64);
#pragma unroll
    for (int c = 0; c < 64; c += 4)
        ho[c >> 2] = make_float4(acc[c], acc[c + 1], acc[c + 2], acc[c + 3]);
}

// ---------------- one message-passing layer ----------------
__global__ __launch_bounds__(LK_THREADS) void layer_kernel(
    const float* __restrict__ h_in, float* __restrict__ h_out,
    const float* __restrict__ pos,
    const int* __restrict__ csr_src, const int* __restrict__ csr_dst,
    const int* __restrict__ row_start, const int* __restrict__ counts,
    const float* __restrict__ W1, const float* __restrict__ B1,
    const float* __restrict__ W2, const float* __restrict__ B2)
{
    __shared__ float hacc[DSTS * HID];
    __shared__ float gbuf[LK_WAVES][64 * GSTRIDE];
    __shared__ int   segb[LK_WAVES][64];

    const int b = blockIdx.y;
    const int dstBase = blockIdx.x * DSTS;
    const int tid = threadIdx.x;
    const int wv = tid >> 6;
    const int lane = tid & 63;

    for (int i = tid; i < DSTS * HID; i += LK_THREADS) hacc[i] = 0.f;
    __syncthreads();

    const int estart = row_start[dstBase];
    const int eend   = row_start[dstBase + DSTS];
    const int ntiles = (eend - estart + 63) >> 6;
    const float* __restrict__ hb = h_in + (size_t)b * N_POINTS * HID;
    float* grow = &gbuf[wv][lane * GSTRIDE];

    for (int t = wv; t < ntiles; t += LK_WAVES) {
        const int ei = estart + t * 64 + lane;
        const bool valid = ei < eend;
        const int src = valid ? csr_src[ei] : 0;
        const int dl  = valid ? (csr_dst[ei] - dstBase) : -1;
        segb[wv][lane] = dl;
        const float* __restrict__ hrow = hb + (size_t)src * HID;
        const float2 ps = *(const float2*)(pos + 2 * src);
        const int dn = valid ? (dstBase + dl) : 0;
        const float2 pd = *(const float2*)(pos + 2 * dn);

        // ---- first matmul: e(68) @ W1(68x64) + b1, lane=edge, weights wave-uniform ----
        float acc[64];
#pragma unroll
        for (int c = 0; c < 64; ++c) acc[c] = B1[c];
#pragma unroll
        for (int c = 0; c < 64; ++c)
            acc[c] += ps.x * W1[c] + ps.y * W1[64 + c] + pd.x * W1[128 + c] + pd.y * W1[192 + c];

        for (int kk = 0; kk < 16; ++kk) {
            const float4 ev = *(const float4*)(hrow + kk * 4);
            const float* __restrict__ wp = W1 + (4 + kk * 4) * 64;
#pragma unroll
            for (int c = 0; c < 64; ++c) {
                float a = acc[c];
                a += ev.x * wp[c];
                a += ev.y * wp[64 + c];
                a += ev.z * wp[128 + c];
                a += ev.w * wp[192 + c];
                acc[c] = a;
            }
        }

        // ---- gelu -> LDS (so second matmul can index k dynamically w/o reg spills) ----
#pragma unroll
        for (int c = 0; c < 64; c += 2) {
            float2 g2;
            g2.x = gelu_f(acc[c]);
            g2.y = gelu_f(acc[c + 1]);
            *(float2*)(grow + c) = g2;
        }

        // ---- second matmul: g(64) @ W2(64x64) + b2 ----
        float m[64];
#pragma unroll
        for (int c = 0; c < 64; ++c) m[c] = B2[c];
        for (int kk = 0; kk < 16; ++kk) {
            const float2 g0 = *(const float2*)(grow + kk * 4);
            const float2 g1 = *(const float2*)(grow + kk * 4 + 2);
            const float* __restrict__ wp = W2 + kk * 4 * 64;
#pragma unroll
            for (int c = 0; c < 64; ++c) {
                float a = m[c];
                a += g0.x * wp[c];
                a += g0.y * wp[64 + c];
                a += g1.x * wp[128 + c];
                a += g1.y * wp[192 + c];
                m[c] = a;
            }
        }

        // ---- transpose m through LDS (reuse grow), segmented reduce into hacc ----
#pragma unroll
        for (int c = 0; c < 64; c += 2)
            *(float2*)(grow + c) = make_float2(m[c], m[c + 1]);

        {
            float racc = 0.f;
            int rseg = -1;
            for (int r = 0; r < 64; ++r) {
                const int s = segb[wv][r];
                const float v = gbuf[wv][r * GSTRIDE + lane];
                if (s != rseg) {
                    if (rseg >= 0) atomicAdd(&hacc[rseg * HID + lane], racc);
                    rseg = s;
                    racc = v;
                } else {
                    racc += v;
                }
            }
            if (rseg >= 0) atomicAdd(&hacc[rseg * HID + lane], racc);
        }
    }
    __syncthreads();

    for (int i = tid; i < DSTS * HID; i += LK_THREADS) {
        const int dl = i >> 6, c = i & 63;
        const int node = dstBase + dl;
        const float cnt = fmaxf((float)counts[node], 1.f);
        const size_t off = ((size_t)b * N_POINTS + node) * HID + c;
        h_out[off] = h_in[off] + hacc[i] / cnt;
    }
}

// ---------------- proj: out = gelu(h@W1+b1)@W2+b2 ----------------
__global__ __launch_bounds__(256) void proj_kernel(
    const float* __restrict__ h, const float* __restrict__ w1, const float* __restrict__ b1,
    const float* __restrict__ w2, const float* __restrict__ b2, float* __restrict__ out)
{
    const int gid = blockIdx.x * 256 + threadIdx.x;   // 0..B*N-1
    float hv[64];
    const float4* hp = (const float4*)(h + (size_t)gid * 64);
#pragma unroll
    for (int c = 0; c < 64; c += 4) {
        float4 v4 = hp[c >> 2];
        hv[c] = v4.x; hv[c + 1] = v4.y; hv[c + 2] = v4.z; hv[c + 3] = v4.w;
    }
    float acc = b2[0];
    for (int jc = 0; jc < 64; ++jc) {
        float t0 = b1[jc * 4 + 0], t1 = b1[jc * 4 + 1], t2 = b1[jc * 4 + 2], t3 = b1[jc * 4 + 3];
#pragma unroll
        for (int k = 0; k < 64; ++k) {
            const float4 w = *(const float4*)(w1 + k * PROJD + jc * 4);
            t0 += hv[k] * w.x; t1 += hv[k] * w.y; t2 += hv[k] * w.z; t3 += hv[k] * w.w;
        }
        const float4 wo = *(const float4*)(w2 + jc * 4);
        acc += gelu_f(t0) * wo.x + gelu_f(t1) * wo.y + gelu_f(t2) * wo.z + gelu_f(t3) * wo.w;
    }
    out[gid] = acc;
}

extern "C" void kernel_launch(void* const* d_in, const int* in_sizes, int n_in,
                              void* d_out, int out_size, void* d_ws, size_t ws_size,
                              hipStream_t stream)
{
    const float* x        = (const float*)d_in[0];
    const float* pos      = (const float*)d_in[1];
    const int*   ei       = (const int*)d_in[2];
    const float* lift_w1  = (const float*)d_in[3];
    const float* lift_b1  = (const float*)d_in[4];
    const float* lift_w2  = (const float*)d_in[5];
    const float* lift_b2  = (const float*)d_in[6];
    const float* kW1      = (const float*)d_in[7];
    const float* kb1      = (const float*)d_in[8];
    const float* kW2      = (const float*)d_in[9];
    const float* kb2      = (const float*)d_in[10];
    const float* proj_w1  = (const float*)d_in[11];
    const float* proj_b1  = (const float*)d_in[12];
    const float* proj_w2  = (const float*)d_in[13];
    const float* proj_b2  = (const float*)d_in[14];
    float* out = (float*)d_out;

    char* ws = (char*)d_ws;
    size_t off = 0;
    float* h0       = (float*)(ws + off); off += (size_t)BATCH * N_POINTS * HID * 4;
    float* h1       = (float*)(ws + off); off += (size_t)BATCH * N_POINTS * HID * 4;
    int* counts     = (int*)(ws + off);   off += (size_t)N_POINTS * 4;
    int* row_start  = (int*)(ws + off);   off += (size_t)(N_POINTS + 2) * 4;
    int* cursor     = (int*)(ws + off);   off += (size_t)N_POINTS * 4;
    int* csr_src    = (int*)(ws + off);   off += (size_t)N_EDGES * 4;
    int* csr_dst    = (int*)(ws + off);   off += (size_t)N_EDGES * 4;

    hipMemsetAsync(counts, 0, N_POINTS * 4, stream);
    hipMemsetAsync(cursor, 0, N_POINTS * 4, stream);

    hist_kernel<<<N_EDGES / 256, 256, 0, stream>>>(ei, counts);
    scan_kernel<<<1, 1024, 0, stream>>>(counts, row_start);
    fill_kernel<<<N_EDGES / 256, 256, 0, stream>>>(ei, row_start, cursor, csr_src, csr_dst);

    lift_kernel<<<BATCH * N_POINTS / 256, 256, 0, stream>>>(
        x, pos, lift_w1, lift_b1, lift_w2, lift_b2, h0);

    float* hin = h0;
    float* hout = h1;
    for (int l = 0; l < NLAYERS; ++l) {
        layer_kernel<<<dim3(N_POINTS / DSTS, BATCH), LK_THREADS, 0, stream>>>(
            hin, hout, pos, csr_src, csr_dst, row_start, counts,
            kW1 + (size_t)l * KIN * HID, kb1 + (size_t)l * HID,
            kW2 + (size_t)l * HID * HID, kb2 + (size_t)l * HID);
        float* tmp = hin; hin = hout; hout = tmp;
    }

    proj_kernel<<<BATCH * N_POINTS / 256, 256, 0, stream>>>(
        hin, proj_w1, proj_b1, proj_w2, proj_b2, out);
}

// Round 2
// 1160.639 us; speedup vs baseline: 2.3421x; 2.3421x over previous
//
#include <hip/hip_runtime.h>
#include <cstdint>
#include <cstddef>

#define N_POINTS 32768
#define KDEG 16
#define N_EDGES (N_POINTS*KDEG)
#define BATCH 2
#define HID 64
#define LIFTD 256
#define PROJD 256
#define KIN 68
#define NLAYERS 4

#define DSTS 32          // dst nodes per block (exclusively owned -> LDS-only aggregation)
#define LK_THREADS 256   // 4 waves
#define LK_WAVES 4
#define ASTR 104         // ushort stride of A tile row (16B-aligned rows: 208 B)
#define GSTR 72          // ushort stride of G tile (144 B rows, 16B-aligned)
#define MSTR 65          // float stride of M tile (2-way bank alias on reduce = free)

typedef unsigned short ushort_t;
typedef short short8 __attribute__((ext_vector_type(8)));
typedef float floatx4 __attribute__((ext_vector_type(4)));

__device__ __forceinline__ float gelu_f(float x) {
    return 0.5f * x * (1.0f + erff(x * 0.70710678118654752440f));
}

__device__ __forceinline__ ushort_t f2bf(float x) {
    unsigned int u = __float_as_uint(x);
    unsigned int r = (u + 0x7FFFu + ((u >> 16) & 1u)) >> 16;   // RNE
    return (ushort_t)r;
}
__device__ __forceinline__ unsigned int pk2bf(float a, float b) {
    return (unsigned int)f2bf(a) | ((unsigned int)f2bf(b) << 16);
}

// ---------------- CSR build ----------------
__global__ void hist_kernel(const int* __restrict__ ei, int* __restrict__ counts) {
    int e = blockIdx.x * 256 + threadIdx.x;
    if (e < N_EDGES) atomicAdd(&counts[ei[N_EDGES + e]], 1);
}

__global__ void scan_kernel(const int* __restrict__ counts, int* __restrict__ row_start) {
    __shared__ int sums[1024];
    const int tid = threadIdx.x;
    const int base = tid * 32;
    int s = 0;
    for (int i = 0; i < 32; ++i) s += counts[base + i];
    sums[tid] = s;
    __syncthreads();
    const int own = s;
    for (int off = 1; off < 1024; off <<= 1) {
        int v = (tid >= off) ? sums[tid - off] : 0;
        __syncthreads();
        sums[tid] += v;
        __syncthreads();
    }
    int run = sums[tid] - own;   // exclusive prefix
    for (int i = 0; i < 32; ++i) { row_start[base + i] = run; run += counts[base + i]; }
    if (tid == 1023) row_start[N_POINTS] = N_EDGES;
}

__global__ void fill_kernel(const int* __restrict__ ei, const int* __restrict__ row_start,
                            int* __restrict__ cursor, int* __restrict__ csr_src,
                            int* __restrict__ csr_dst) {
    int e = blockIdx.x * 256 + threadIdx.x;
    if (e < N_EDGES) {
        int s = ei[e], d = ei[N_EDGES + e];
        int p = atomicAdd(&cursor[d], 1);
        int idx = row_start[d] + p;
        csr_src[idx] = s;
        csr_dst[idx] = d;
    }
}

// -------- weight pre-swizzle into MFMA B-fragment order (bf16) --------
// W1' rows: [0..63]=W1[4..67] (h part), [64..67]=W1[0..3] (pos part), [68]=b1, [69..95]=0
// frag f<12 : GEMM1 (kc=f>>2 in 0..2, ct=f&3);  f>=12: GEMM2 (kc, ct of f-12)
// element j of lane: B'[k=kc*32+(lane>>4)*8+j][n=ct*16+(lane&15)]
__global__ void wprep_kernel(const float* __restrict__ kW1, const float* __restrict__ kb1,
                             const float* __restrict__ kW2, ushort_t* __restrict__ wfrag) {
    int t = blockIdx.x * 256 + threadIdx.x;
    if (t >= NLAYERS * 20 * 64) return;
    const int lane = t & 63;
    const int f = (t >> 6) % 20;
    const int l = t / (20 * 64);
    const int n = ((f < 12 ? (f & 3) : ((f - 12) & 3)) * 16) + (lane & 15);
    ushort_t o[8];
    if (f < 12) {
        const int kc = f >> 2;
        const float* W1 = kW1 + (size_t)l * KIN * HID;
        const float* B1 = kb1 + (size_t)l * HID;
#pragma unroll
        for (int j = 0; j < 8; ++j) {
            const int k = kc * 32 + ((lane >> 4) & 3) * 8 + j;
            float v;
            if (k < 64) v = W1[(size_t)(4 + k) * HID + n];
            else if (k < 68) v = W1[(size_t)(k - 64) * HID + n];
            else if (k == 68) v = B1[n];
            else v = 0.f;
            o[j] = f2bf(v);
        }
    } else {
        const int kc = (f - 12) >> 2;
        const float* W2 = kW2 + (size_t)l * HID * HID;
#pragma unroll
        for (int j = 0; j < 8; ++j) {
            const int k = kc * 32 + ((lane >> 4) & 3) * 8 + j;
            o[j] = f2bf(W2[(size_t)k * HID + n]);
        }
    }
    ushort_t* dst = wfrag + ((size_t)(l * 20 + f) * 64 + lane) * 8;
#pragma unroll
    for (int j = 0; j < 8; ++j) dst[j] = o[j];
}

// ---------------- lift: h = gelu([x,pos]@W1+b1)@W2+b2 ----------------
__global__ __launch_bounds__(256) void lift_kernel(
    const float* __restrict__ x, const float* __restrict__ pos,
    const float* __restrict__ w1, const float* __restrict__ b1,
    const float* __restrict__ w2, const float* __restrict__ b2,
    float* __restrict__ h)
{
    const int gid = blockIdx.x * 256 + threadIdx.x;
    const int i = gid & (N_POINTS - 1);
    const float x0 = x[(size_t)gid * 3 + 0];
    const float x1 = x[(size_t)gid * 3 + 1];
    const float x2 = x[(size_t)gid * 3 + 2];
    const float2 p = *(const float2*)(pos + 2 * i);

    float acc[64];
#pragma unroll
    for (int c = 0; c < 64; ++c) acc[c] = b2[c];

    for (int j = 0; j < LIFTD; ++j) {
        float tv = b1[j] + x0 * w1[j] + x1 * w1[LIFTD + j] + x2 * w1[2 * LIFTD + j]
                 + p.x * w1[3 * LIFTD + j] + p.y * w1[4 * LIFTD + j];
        const float g = gelu_f(tv);
        const float* __restrict__ wp = w2 + j * 64;
#pragma unroll
        for (int c = 0; c < 64; ++c) acc[c] += g * wp[c];
    }
    float4* ho = (float4*)(h + (size_t)gid * 64);
#pragma unroll
    for (int c = 0; c < 64; c += 4)
        ho[c >> 2] = make_float4(acc[c], acc[c + 1], acc[c + 2], acc[c + 3]);
}

// ---------------- one message-passing layer (MFMA) ----------------
__global__ __launch_bounds__(LK_THREADS, 3) void layer_kernel(
    const float* __restrict__ h_in, float* __restrict__ h_out,
    const float* __restrict__ pos,
    const int* __restrict__ csr_src, const int* __restrict__ csr_dst,
    const int* __restrict__ row_start, const int* __restrict__ counts,
    const ushort_t* __restrict__ wfrag, const float* __restrict__ B2)
{
    __shared__ ushort_t Atile[LK_WAVES][16 * ASTR];   // 4 x 3328 B
    __shared__ float    GMt[LK_WAVES][16 * MSTR];     // 4 x 4160 B (G bf16 overlays M f32)
    __shared__ float    hacc[DSTS * HID];             // 8 KB
    __shared__ int      segb[LK_WAVES][16];

    const int b = blockIdx.y;
    const int dstBase = blockIdx.x * DSTS;
    const int tid = threadIdx.x;
    const int wv = tid >> 6;
    const int lane = tid & 63;
    const int m16 = lane & 15;
    const int q = lane >> 4;     // quad 0..3

    for (int i = tid; i < DSTS * HID; i += LK_THREADS) hacc[i] = 0.f;

    // zero A-tile pad cols [72..95] once (never overwritten later)
    {
        ushort_t* At = &Atile[wv][0];
        for (int i = lane; i < 16 * 24; i += 64) {
            const int r = i / 24, c = 72 + (i % 24);
            At[r * ASTR + c] = 0;
        }
    }
    __syncthreads();

    // resident weight fragments (20 x 16B = 80 VGPRs)
    const short8* wf = (const short8*)wfrag;
    short8 w1f[3][4], w2f[2][4];
#pragma unroll
    for (int kc = 0; kc < 3; ++kc)
#pragma unroll
        for (int ct = 0; ct < 4; ++ct) w1f[kc][ct] = wf[(kc * 4 + ct) * 64 + lane];
#pragma unroll
    for (int kc = 0; kc < 2; ++kc)
#pragma unroll
        for (int ct = 0; ct < 4; ++ct) w2f[kc][ct] = wf[(12 + kc * 4 + ct) * 64 + lane];
    float b2r[4];
#pragma unroll
    for (int ct = 0; ct < 4; ++ct) b2r[ct] = B2[ct * 16 + m16];

    const int estart = row_start[dstBase];
    const int eend   = row_start[dstBase + DSTS];
    const int ntiles = (eend - estart + 15) >> 4;
    const float* __restrict__ hb = h_in + (size_t)b * N_POINTS * HID;

    ushort_t* At = &Atile[wv][0];
    float*    GM = &GMt[wv][0];
    ushort_t* Gt = (ushort_t*)GM;

    for (int t = wv; t < ntiles; t += LK_WAVES) {
        const int e0 = estart + t * 16;

        // ---- gather h[src] fp32 -> bf16 A-tile rows (lane covers 16 cols of one row) ----
        {
            const int row = lane >> 2, ch = lane & 3;
            const int ec = min(e0 + row, eend - 1);
            const int src = csr_src[ec];
            const float* hr = hb + (size_t)src * HID + ch * 16;
            const float4 v0 = *(const float4*)(hr + 0);
            const float4 v1 = *(const float4*)(hr + 4);
            const float4 v2 = *(const float4*)(hr + 8);
            const float4 v3 = *(const float4*)(hr + 12);
            uint4 wA, wB;
            wA.x = pk2bf(v0.x, v0.y); wA.y = pk2bf(v0.z, v0.w);
            wA.z = pk2bf(v1.x, v1.y); wA.w = pk2bf(v1.z, v1.w);
            wB.x = pk2bf(v2.x, v2.y); wB.y = pk2bf(v2.z, v2.w);
            wB.z = pk2bf(v3.x, v3.y); wB.w = pk2bf(v3.z, v3.w);
            *(uint4*)&At[row * ASTR + ch * 16 + 0] = wA;
            *(uint4*)&At[row * ASTR + ch * 16 + 8] = wB;
        }
        // ---- pos features + segment ids (lanes 0..15, one edge each) ----
        if (lane < 16) {
            const int e = e0 + lane;
            const bool valid = e < eend;
            const int ec = valid ? e : (eend - 1);
            const int s2 = csr_src[ec];
            const int d2 = csr_dst[ec];
            const float2 ps = *(const float2*)(pos + 2 * s2);
            const float2 pd = *(const float2*)(pos + 2 * d2);
            uint4 pw;
            pw.x = pk2bf(ps.x, ps.y);
            pw.y = pk2bf(pd.x, pd.y);
            pw.z = pk2bf(1.0f, 0.0f);
            pw.w = 0u;
            *(uint4*)&At[lane * ASTR + 64] = pw;
            segb[wv][lane] = valid ? (d2 - dstBase) : -1;
        }

        // ---- GEMM1: A(16x96) @ W1'(96x64), K in 3 chunks of 32 ----
        short8 a0 = *(const short8*)&At[m16 * ASTR +  0 + q * 8];
        short8 a1 = *(const short8*)&At[m16 * ASTR + 32 + q * 8];
        short8 a2 = *(const short8*)&At[m16 * ASTR + 64 + q * 8];
        floatx4 acc[4];
#pragma unroll
        for (int ct = 0; ct < 4; ++ct) {
            floatx4 c = {0.f, 0.f, 0.f, 0.f};
            c = __builtin_amdgcn_mfma_f32_16x16x32_bf16(a0, w1f[0][ct], c, 0, 0, 0);
            c = __builtin_amdgcn_mfma_f32_16x16x32_bf16(a1, w1f[1][ct], c, 0, 0, 0);
            c = __builtin_amdgcn_mfma_f32_16x16x32_bf16(a2, w1f[2][ct], c, 0, 0, 0);
            acc[ct] = c;
        }

        // ---- gelu -> G (bf16, A-layout staging via LDS) ----
#pragma unroll
        for (int ct = 0; ct < 4; ++ct)
#pragma unroll
            for (int r = 0; r < 4; ++r)
                Gt[(q * 4 + r) * GSTR + ct * 16 + m16] = f2bf(gelu_f(acc[ct][r]));

        // ---- GEMM2: G(16x64) @ W2(64x64) ----
        short8 g0 = *(const short8*)&Gt[m16 * GSTR +  0 + q * 8];
        short8 g1 = *(const short8*)&Gt[m16 * GSTR + 32 + q * 8];
        floatx4 mm[4];
#pragma unroll
        for (int ct = 0; ct < 4; ++ct) {
            floatx4 c = {0.f, 0.f, 0.f, 0.f};
            c = __builtin_amdgcn_mfma_f32_16x16x32_bf16(g0, w2f[0][ct], c, 0, 0, 0);
            c = __builtin_amdgcn_mfma_f32_16x16x32_bf16(g1, w2f[1][ct], c, 0, 0, 0);
            mm[ct] = c;
        }

        // ---- M (+b2) -> LDS f32 tile ----
#pragma unroll
        for (int ct = 0; ct < 4; ++ct)
#pragma unroll
            for (int r = 0; r < 4; ++r)
                GM[(q * 4 + r) * MSTR + ct * 16 + m16] = mm[ct][r] + b2r[ct];

        // ---- segmented reduce rows -> hacc (lane = column) ----
        {
            float racc = 0.f;
            int rseg = -1;
#pragma unroll
            for (int r = 0; r < 16; ++r) {
                const int s = segb[wv][r];
                const float v = GM[r * MSTR + lane];
                if (s != rseg) {
                    if (rseg >= 0) atomicAdd(&hacc[rseg * HID + lane], racc);
                    rseg = s;
                    racc = v;
                } else {
                    racc += v;
                }
            }
            if (rseg >= 0) atomicAdd(&hacc[rseg * HID + lane], racc);
        }
    }
    __syncthreads();

    for (int i = tid; i < DSTS * HID; i += LK_THREADS) {
        const int dl = i >> 6, c = i & 63;
        const int node = dstBase + dl;
        const float cnt = fmaxf((float)counts[node], 1.f);
        const size_t off = ((size_t)b * N_POINTS + node) * HID + c;
        h_out[off] = h_in[off] + hacc[i] / cnt;
    }
}

// ---------------- proj: out = gelu(h@W1+b1)@W2+b2 ----------------
__global__ __launch_bounds__(256) void proj_kernel(
    const float* __restrict__ h, const float* __restrict__ w1, const float* __restrict__ b1,
    const float* __restrict__ w2, const float* __restrict__ b2, float* __restrict__ out)
{
    const int gid = blockIdx.x * 256 + threadIdx.x;
    float hv[64];
    const float4* hp = (const float4*)(h + (size_t)gid * 64);
#pragma unroll
    for (int c = 0; c < 64; c += 4) {
        float4 v4 = hp[c >> 2];
        hv[c] = v4.x; hv[c + 1] = v4.y; hv[c + 2] = v4.z; hv[c + 3] = v4.w;
    }
    float acc = b2[0];
    for (int jc = 0; jc < 64; ++jc) {
        float t0 = b1[jc * 4 + 0], t1 = b1[jc * 4 + 1], t2 = b1[jc * 4 + 2], t3 = b1[jc * 4 + 3];
#pragma unroll
        for (int k = 0; k < 64; ++k) {
            const float4 w = *(const float4*)(w1 + k * PROJD + jc * 4);
            t0 += hv[k] * w.x; t1 += hv[k] * w.y; t2 += hv[k] * w.z; t3 += hv[k] * w.w;
        }
        const float4 wo = *(const float4*)(w2 + jc * 4);
        acc += gelu_f(t0) * wo.x + gelu_f(t1) * wo.y + gelu_f(t2) * wo.z + gelu_f(t3) * wo.w;
    }
    out[gid] = acc;
}

extern "C" void kernel_launch(void* const* d_in, const int* in_sizes, int n_in,
                              void* d_out, int out_size, void* d_ws, size_t ws_size,
                              hipStream_t stream)
{
    const float* x        = (const float*)d_in[0];
    const float* pos      = (const float*)d_in[1];
    const int*   ei       = (const int*)d_in[2];
    const float* lift_w1  = (const float*)d_in[3];
    const float* lift_b1  = (const float*)d_in[4];
    const float* lift_w2  = (const float*)d_in[5];
    const float* lift_b2  = (const float*)d_in[6];
    const float* kW1      = (const float*)d_in[7];
    const float* kb1      = (const float*)d_in[8];
    const float* kW2      = (const float*)d_in[9];
    const float* kb2      = (const float*)d_in[10];
    const float* proj_w1  = (const float*)d_in[11];
    const float* proj_b1  = (const float*)d_in[12];
    const float* proj_w2  = (const float*)d_in[13];
    const float* proj_b2  = (const float*)d_in[14];
    float* out = (float*)d_out;

    char* ws = (char*)d_ws;
    size_t off = 0;
    float* h0       = (float*)(ws + off); off += (size_t)BATCH * N_POINTS * HID * 4;
    float* h1       = (float*)(ws + off); off += (size_t)BATCH * N_POINTS * HID * 4;
    int* counts     = (int*)(ws + off);   off += (size_t)N_POINTS * 4;
    int* row_start  = (int*)(ws + off);   off += (size_t)(N_POINTS + 4) * 4;
    int* cursor     = (int*)(ws + off);   off += (size_t)N_POINTS * 4;   // dead after fill; wfrag aliases it
    int* csr_src    = (int*)(ws + off);   off += (size_t)N_EDGES * 4;
    int* csr_dst    = (int*)(ws + off);   off += (size_t)N_EDGES * 4;
    ushort_t* wfrag = (ushort_t*)cursor;  // 4*20*64*8*2 = 80 KB <= 128 KB (cursor)

    hipMemsetAsync(counts, 0, N_POINTS * 4, stream);
    hipMemsetAsync(cursor, 0, N_POINTS * 4, stream);

    hist_kernel<<<N_EDGES / 256, 256, 0, stream>>>(ei, counts);
    scan_kernel<<<1, 1024, 0, stream>>>(counts, row_start);
    fill_kernel<<<N_EDGES / 256, 256, 0, stream>>>(ei, row_start, cursor, csr_src, csr_dst);
    wprep_kernel<<<(NLAYERS * 20 * 64 + 255) / 256, 256, 0, stream>>>(kW1, kb1, kW2, wfrag);

    lift_kernel<<<BATCH * N_POINTS / 256, 256, 0, stream>>>(
        x, pos, lift_w1, lift_b1, lift_w2, lift_b2, h0);

    float* hin = h0;
    float* hout = h1;
    for (int l = 0; l < NLAYERS; ++l) {
        layer_kernel<<<dim3(N_POINTS / DSTS, BATCH), LK_THREADS, 0, stream>>>(
            hin, hout, pos, csr_src, csr_dst, row_start, counts,
            wfrag + (size_t)l * 20 * 64 * 8, kb2 + (size_t)l * HID);
        float* tmp = hin; hin = hout; hout = tmp;
    }

    proj_kernel<<<BATCH * N_POINTS / 256, 256, 0, stream>>>(
        hin, proj_w1, proj_b1, proj_w2, proj_b2, out);
}

// Round 3
// 853.366 us; speedup vs baseline: 3.1855x; 1.3601x over previous
//
#include <hip/hip_runtime.h>
#include <cstdint>
#include <cstddef>

#define N_POINTS 32768
#define KDEG 16
#define N_EDGES (N_POINTS*KDEG)
#define BATCH 2
#define HID 64
#define LIFTD 256
#define PROJD 256
#define KIN 68
#define NLAYERS 4

#define DSTS 32          // dst nodes per block (exclusively owned -> LDS-only aggregation)
#define LK_THREADS 256   // 4 waves
#define LK_WAVES 4
#define ASTR 104         // ushort stride of layer A tile row (208 B, 16B-aligned)
#define GSTR 72          // ushort stride of layer G tile (144 B rows, 16B-aligned)

#define LASTR 40         // lift A tile stride (80 B rows, 16B-aligned)
#define LGSTR 264        // lift G tile stride (528 B rows, 16B-aligned)
#define PASTR 72         // proj A tile stride (144 B rows)

// wfrag slot layout (each slot = 64 lanes x 8 ushorts = 1KB per frag, 16B per lane-slot)
// slots are indexed as (frag*64 + lane), payload 8 ushorts
#define FR_EDGE 0        // 80 frags (4 layers x 20)
#define FR_LW1  80       // 16 frags: lift W1' (K=32 pad: x3,pos2,bias,zeros)
#define FR_LW2  96       // 32 frags: lift W2' (8 kc x 4 ct)
#define FR_TOT  128      // 128 frags * 1KB = 128KB  (== cursor region, exactly)

typedef unsigned short ushort_t;
typedef short short8 __attribute__((ext_vector_type(8)));
typedef float floatx4 __attribute__((ext_vector_type(4)));

__device__ __forceinline__ float gelu_f(float x) {
    return 0.5f * x * (1.0f + erff(x * 0.70710678118654752440f));
}

__device__ __forceinline__ ushort_t f2bf(float x) {
    unsigned int u = __float_as_uint(x);
    unsigned int r = (u + 0x7FFFu + ((u >> 16) & 1u)) >> 16;   // RNE
    return (ushort_t)r;
}
__device__ __forceinline__ unsigned int pk2bf(float a, float b) {
    return (unsigned int)f2bf(a) | ((unsigned int)f2bf(b) << 16);
}

// ---------------- CSR build ----------------
__global__ void hist_kernel(const int* __restrict__ ei, int* __restrict__ counts) {
    int e = blockIdx.x * 256 + threadIdx.x;
    if (e < N_EDGES) atomicAdd(&counts[ei[N_EDGES + e]], 1);
}

__global__ void scan_kernel(const int* __restrict__ counts, int* __restrict__ row_start) {
    __shared__ int sums[1024];
    const int tid = threadIdx.x;
    const int base = tid * 32;
    int s = 0;
    for (int i = 0; i < 32; ++i) s += counts[base + i];
    sums[tid] = s;
    __syncthreads();
    const int own = s;
    for (int off = 1; off < 1024; off <<= 1) {
        int v = (tid >= off) ? sums[tid - off] : 0;
        __syncthreads();
        sums[tid] += v;
        __syncthreads();
    }
    int run = sums[tid] - own;   // exclusive prefix
    for (int i = 0; i < 32; ++i) { row_start[base + i] = run; run += counts[base + i]; }
    if (tid == 1023) row_start[N_POINTS] = N_EDGES;
}

__global__ void fill_kernel(const int* __restrict__ ei, const int* __restrict__ row_start,
                            int* __restrict__ cursor, int* __restrict__ csr_src,
                            int* __restrict__ csr_dst) {
    int e = blockIdx.x * 256 + threadIdx.x;
    if (e < N_EDGES) {
        int s = ei[e], d = ei[N_EDGES + e];
        int p = atomicAdd(&cursor[d], 1);
        int idx = row_start[d] + p;
        csr_src[idx] = s;
        csr_dst[idx] = d;
    }
}

// -------- weight pre-swizzle into MFMA B-fragment order (bf16) --------
// B'[k = kc*32 + (lane>>4)*8 + j][n = ct*16 + (lane&15)]
__global__ void wprep_kernel(const float* __restrict__ kW1, const float* __restrict__ kb1,
                             const float* __restrict__ kW2,
                             const float* __restrict__ lw1, const float* __restrict__ lb1,
                             const float* __restrict__ lw2,
                             ushort_t* __restrict__ wfrag) {
    int t = blockIdx.x * 256 + threadIdx.x;
    if (t >= FR_TOT * 64) return;
    const int lane = t & 63;
    const int fi = t >> 6;
    const int m16 = lane & 15;
    const int qb = ((lane >> 4) & 3) * 8;
    ushort_t o[8];
    if (fi < FR_LW1) {
        // edge-MLP frags: layer l, frag f (0..11 GEMM1, 12..19 GEMM2)
        const int l = fi / 20, f = fi % 20;
        const int n = ((f < 12 ? (f & 3) : ((f - 12) & 3)) * 16) + m16;
        if (f < 12) {
            const int kc = f >> 2;
            const float* W1 = kW1 + (size_t)l * KIN * HID;
            const float* B1 = kb1 + (size_t)l * HID;
#pragma unroll
            for (int j = 0; j < 8; ++j) {
                const int k = kc * 32 + qb + j;
                float v;
                if (k < 64) v = W1[(size_t)(4 + k) * HID + n];
                else if (k < 68) v = W1[(size_t)(k - 64) * HID + n];
                else if (k == 68) v = B1[n];
                else v = 0.f;
                o[j] = f2bf(v);
            }
        } else {
            const int kc = (f - 12) >> 2;
            const float* W2 = kW2 + (size_t)l * HID * HID;
#pragma unroll
            for (int j = 0; j < 8; ++j)
                o[j] = f2bf(W2[(size_t)(kc * 32 + qb + j) * HID + n]);
        }
    } else if (fi < FR_LW2) {
        // lift W1': rows k: 0..4 = lw1 rows (x0,x1,x2,px,py), 5 = b1, 6..31 = 0
        const int ct = fi - FR_LW1;
        const int n = ct * 16 + m16;
#pragma unroll
        for (int j = 0; j < 8; ++j) {
            const int k = qb + j;
            float v;
            if (k < 5) v = lw1[(size_t)k * LIFTD + n];
            else if (k == 5) v = lb1[n];
            else v = 0.f;
            o[j] = f2bf(v);
        }
    } else {
        // lift W2': kc 0..7, ct 0..3
        const int idx = fi - FR_LW2;
        const int kc = idx >> 2, ct = idx & 3;
        const int n = ct * 16 + m16;
#pragma unroll
        for (int j = 0; j < 8; ++j)
            o[j] = f2bf(lw2[(size_t)(kc * 32 + qb + j) * HID + n]);
    }
    ushort_t* dst = wfrag + ((size_t)fi * 64 + lane) * 8;
#pragma unroll
    for (int j = 0; j < 8; ++j) dst[j] = o[j];
}

// proj W1' frags (2 kc x 16 ct = 32 frags) -> pfrag (aliases csr_src, launched after layers)
__global__ void wprep_proj_kernel(const float* __restrict__ pw1, ushort_t* __restrict__ pfrag) {
    int t = blockIdx.x * 256 + threadIdx.x;
    if (t >= 32 * 64) return;
    const int lane = t & 63;
    const int fi = t >> 6;           // kc*16 + ct
    const int kc = fi >> 4, ct = fi & 15;
    const int n = ct * 16 + (lane & 15);
    const int qb = ((lane >> 4) & 3) * 8;
    ushort_t* dst = pfrag + ((size_t)fi * 64 + lane) * 8;
#pragma unroll
    for (int j = 0; j < 8; ++j)
        dst[j] = f2bf(pw1[(size_t)(kc * 32 + qb + j) * PROJD + n]);
}

// ---------------- lift (MFMA): h = gelu([x,pos,1]@W1')@W2' + b2 ----------------
__global__ __launch_bounds__(256) void lift_kernel(
    const float* __restrict__ x, const float* __restrict__ pos,
    const ushort_t* __restrict__ wfrag, const float* __restrict__ lb2,
    float* __restrict__ h)
{
    __shared__ __align__(16) ushort_t WF[3072 * 8];          // 48KB: W1' (slots 0..1023) + W2' (1024..3071)
    __shared__ __align__(16) ushort_t LA[4][16 * LASTR];     // 5KB
    __shared__ __align__(16) ushort_t LG[4][16 * LGSTR];     // 33KB

    const int tid = threadIdx.x;
    const int wv = tid >> 6;
    const int lane = tid & 63;
    const int m16 = lane & 15;
    const int q = lane >> 4;

    // preload weight frags to LDS
    {
        const uint4* gw = (const uint4*)(wfrag + (size_t)FR_LW1 * 64 * 8);
        uint4* lw = (uint4*)WF;
        for (int i = tid; i < 3072; i += 256) lw[i] = gw[i];
    }
    __syncthreads();

    const int gid0 = (blockIdx.x * 4 + wv) * 16;
    ushort_t* At = &LA[wv][0];
    ushort_t* Gt = &LG[wv][0];

    if (lane < 16) {
        const int g = gid0 + lane;
        const int i = g & (N_POINTS - 1);
        const float x0 = x[3 * (size_t)g], x1 = x[3 * (size_t)g + 1], x2 = x[3 * (size_t)g + 2];
        const float2 p = *(const float2*)(pos + 2 * i);
        uint4 w;
        w.x = pk2bf(x0, x1);
        w.y = pk2bf(x2, p.x);
        w.z = pk2bf(p.y, 1.0f);
        w.w = 0u;
        uint4 z; z.x = z.y = z.z = z.w = 0u;
        *(uint4*)&At[lane * LASTR + 0] = w;
        *(uint4*)&At[lane * LASTR + 8] = z;
        *(uint4*)&At[lane * LASTR + 16] = z;
        *(uint4*)&At[lane * LASTR + 24] = z;
    }

    // GEMM1: A(16x32) @ W1'(32x256)
    const short8 a = *(const short8*)&At[m16 * LASTR + q * 8];
    floatx4 acc[16];
#pragma unroll
    for (int ct = 0; ct < 16; ++ct) {
        const short8 bf = *(const short8*)&WF[((size_t)ct * 64 + lane) * 8];
        floatx4 c = {0.f, 0.f, 0.f, 0.f};
        acc[ct] = __builtin_amdgcn_mfma_f32_16x16x32_bf16(a, bf, c, 0, 0, 0);
    }

    // gelu -> G (bf16, A-layout)
#pragma unroll
    for (int ct = 0; ct < 16; ++ct)
#pragma unroll
        for (int r = 0; r < 4; ++r)
            Gt[(q * 4 + r) * LGSTR + ct * 16 + m16] = f2bf(gelu_f(acc[ct][r]));

    // GEMM2: G(16x256) @ W2'(256x64)
    floatx4 acc2[4];
#pragma unroll
    for (int ct = 0; ct < 4; ++ct) { floatx4 z = {0.f, 0.f, 0.f, 0.f}; acc2[ct] = z; }
#pragma unroll
    for (int kc = 0; kc < 8; ++kc) {
        const short8 g = *(const short8*)&Gt[m16 * LGSTR + kc * 32 + q * 8];
#pragma unroll
        for (int ct = 0; ct < 4; ++ct) {
            const short8 bf = *(const short8*)&WF[((size_t)(1024 + (kc * 4 + ct) * 64) + lane) * 8];
            acc2[ct] = __builtin_amdgcn_mfma_f32_16x16x32_bf16(g, bf, acc2[ct], 0, 0, 0);
        }
    }

    // epilogue: + b2, store fp32
    float b2r[4];
#pragma unroll
    for (int ct = 0; ct < 4; ++ct) b2r[ct] = lb2[ct * 16 + m16];
#pragma unroll
    for (int ct = 0; ct < 4; ++ct)
#pragma unroll
        for (int r = 0; r < 4; ++r)
            h[(size_t)(gid0 + q * 4 + r) * HID + ct * 16 + m16] = acc2[ct][r] + b2r[ct];
}

// ---------------- one message-passing layer (MFMA) ----------------
__global__ __launch_bounds__(LK_THREADS, 3) void layer_kernel(
    const float* __restrict__ h_in, float* __restrict__ h_out,
    const float* __restrict__ pos,
    const int* __restrict__ csr_src, const int* __restrict__ csr_dst,
    const int* __restrict__ row_start, const int* __restrict__ counts,
    const ushort_t* __restrict__ wfrag, const float* __restrict__ B2)
{
    __shared__ __align__(16) ushort_t Atile[LK_WAVES][16 * ASTR];   // 13KB
    __shared__ __align__(16) ushort_t Gts[LK_WAVES][16 * GSTR];     // 9KB
    __shared__ float hacc[DSTS * HID];                              // 8KB
    __shared__ int   segb[LK_WAVES][16];

    const int b = blockIdx.y;
    const int dstBase = blockIdx.x * DSTS;
    const int tid = threadIdx.x;
    const int wv = tid >> 6;
    const int lane = tid & 63;
    const int m16 = lane & 15;
    const int q = lane >> 4;

    for (int i = tid; i < DSTS * HID; i += LK_THREADS) hacc[i] = 0.f;

    // zero A-tile pad cols [72..95] once
    {
        ushort_t* At = &Atile[wv][0];
        for (int i = lane; i < 16 * 24; i += 64) {
            const int r = i / 24, c = 72 + (i % 24);
            At[r * ASTR + c] = 0;
        }
    }
    __syncthreads();

    // resident weight fragments
    const short8* wf = (const short8*)wfrag;
    short8 w1f[3][4], w2f[2][4];
#pragma unroll
    for (int kc = 0; kc < 3; ++kc)
#pragma unroll
        for (int ct = 0; ct < 4; ++ct) w1f[kc][ct] = wf[(kc * 4 + ct) * 64 + lane];
#pragma unroll
    for (int kc = 0; kc < 2; ++kc)
#pragma unroll
        for (int ct = 0; ct < 4; ++ct) w2f[kc][ct] = wf[(12 + kc * 4 + ct) * 64 + lane];
    float b2r[4];
#pragma unroll
    for (int ct = 0; ct < 4; ++ct) b2r[ct] = B2[ct * 16 + m16];

    const int estart = row_start[dstBase];
    const int eend   = row_start[dstBase + DSTS];
    const int ntiles = (eend - estart + 15) >> 4;
    const float* __restrict__ hb = h_in + (size_t)b * N_POINTS * HID;

    ushort_t* At = &Atile[wv][0];
    ushort_t* Gt = &Gts[wv][0];

    const int grow = lane >> 2, gch = lane & 3;

    // prefetch tile wv
    float4 p0, p1, p2, p3;
    int t = wv;
    if (t < ntiles) {
        const int ec = min(estart + t * 16 + grow, eend - 1);
        const int src = csr_src[ec];
        const float4* hr = (const float4*)(hb + (size_t)src * HID + gch * 16);
        p0 = hr[0]; p1 = hr[1]; p2 = hr[2]; p3 = hr[3];
    }

    for (; t < ntiles; t += LK_WAVES) {
        const int e0 = estart + t * 16;

        // ---- A-tile write from prefetched registers ----
        {
            uint4 wA, wB;
            wA.x = pk2bf(p0.x, p0.y); wA.y = pk2bf(p0.z, p0.w);
            wA.z = pk2bf(p1.x, p1.y); wA.w = pk2bf(p1.z, p1.w);
            wB.x = pk2bf(p2.x, p2.y); wB.y = pk2bf(p2.z, p2.w);
            wB.z = pk2bf(p3.x, p3.y); wB.w = pk2bf(p3.z, p3.w);
            *(uint4*)&At[grow * ASTR + gch * 16 + 0] = wA;
            *(uint4*)&At[grow * ASTR + gch * 16 + 8] = wB;
        }
        // ---- pos features + segment ids (lanes 0..15) ----
        if (lane < 16) {
            const int e = e0 + lane;
            const bool valid = e < eend;
            const int ec = valid ? e : (eend - 1);
            const int s2 = csr_src[ec];
            const int d2 = csr_dst[ec];
            const float2 ps = *(const float2*)(pos + 2 * s2);
            const float2 pd = *(const float2*)(pos + 2 * d2);
            uint4 pw;
            pw.x = pk2bf(ps.x, ps.y);
            pw.y = pk2bf(pd.x, pd.y);
            pw.z = pk2bf(1.0f, 0.0f);
            pw.w = 0u;
            *(uint4*)&At[lane * ASTR + 64] = pw;
            segb[wv][lane] = valid ? (d2 - dstBase) : -1;
        }

        // ---- prefetch next tile's gather (overlaps MFMA section) ----
        const int tn = t + LK_WAVES;
        if (tn < ntiles) {
            const int ec = min(estart + tn * 16 + grow, eend - 1);
            const int src = csr_src[ec];
            const float4* hr = (const float4*)(hb + (size_t)src * HID + gch * 16);
            p0 = hr[0]; p1 = hr[1]; p2 = hr[2]; p3 = hr[3];
        }

        // ---- GEMM1: A(16x96) @ W1'(96x64) ----
        short8 a0 = *(const short8*)&At[m16 * ASTR +  0 + q * 8];
        short8 a1 = *(const short8*)&At[m16 * ASTR + 32 + q * 8];
        short8 a2 = *(const short8*)&At[m16 * ASTR + 64 + q * 8];
        floatx4 acc[4];
#pragma unroll
        for (int ct = 0; ct < 4; ++ct) {
            floatx4 c = {0.f, 0.f, 0.f, 0.f};
            c = __builtin_amdgcn_mfma_f32_16x16x32_bf16(a0, w1f[0][ct], c, 0, 0, 0);
            c = __builtin_amdgcn_mfma_f32_16x16x32_bf16(a1, w1f[1][ct], c, 0, 0, 0);
            c = __builtin_amdgcn_mfma_f32_16x16x32_bf16(a2, w1f[2][ct], c, 0, 0, 0);
            acc[ct] = c;
        }

        // ---- gelu -> G (bf16, A-layout via LDS) ----
#pragma unroll
        for (int ct = 0; ct < 4; ++ct)
#pragma unroll
            for (int r = 0; r < 4; ++r)
                Gt[(q * 4 + r) * GSTR + ct * 16 + m16] = f2bf(gelu_f(acc[ct][r]));

        // ---- GEMM2: G(16x64) @ W2(64x64) ----
        short8 g0 = *(const short8*)&Gt[m16 * GSTR +  0 + q * 8];
        short8 g1 = *(const short8*)&Gt[m16 * GSTR + 32 + q * 8];
        floatx4 mm[4];
#pragma unroll
        for (int ct = 0; ct < 4; ++ct) {
            floatx4 c = {0.f, 0.f, 0.f, 0.f};
            c = __builtin_amdgcn_mfma_f32_16x16x32_bf16(g0, w2f[0][ct], c, 0, 0, 0);
            c = __builtin_amdgcn_mfma_f32_16x16x32_bf16(g1, w2f[1][ct], c, 0, 0, 0);
            mm[ct] = c;
        }

        // ---- segmented reduce straight from C-layout registers into hacc ----
        {
            int ss[4];
#pragma unroll
            for (int r = 0; r < 4; ++r) ss[r] = segb[wv][q * 4 + r];
#pragma unroll
            for (int ct = 0; ct < 4; ++ct) {
                const int col = ct * 16 + m16;
                float run = mm[ct][0] + b2r[ct];
                int cs = ss[0];
#pragma unroll
                for (int r = 1; r < 4; ++r) {
                    const float v = mm[ct][r] + b2r[ct];
                    if (ss[r] == cs) {
                        run += v;
                    } else {
                        if (cs >= 0) atomicAdd(&hacc[cs * HID + col], run);
                        cs = ss[r];
                        run = v;
                    }
                }
                if (cs >= 0) atomicAdd(&hacc[cs * HID + col], run);
            }
        }
    }
    __syncthreads();

    for (int i = tid; i < DSTS * HID; i += LK_THREADS) {
        const int dl = i >> 6, c = i & 63;
        const int node = dstBase + dl;
        const float cnt = fmaxf((float)counts[node], 1.f);
        const size_t off = ((size_t)b * N_POINTS + node) * HID + c;
        h_out[off] = h_in[off] + hacc[i] / cnt;
    }
}

// ---------------- proj (MFMA GEMM1 + VALU dot GEMM2) ----------------
__global__ __launch_bounds__(256) void proj_kernel(
    const float* __restrict__ h, const ushort_t* __restrict__ pfrag,
    const float* __restrict__ b1, const float* __restrict__ w2,
    const float* __restrict__ b2, float* __restrict__ out)
{
    __shared__ __align__(16) ushort_t WF[2048 * 8];          // 32KB: proj W1' frags
    __shared__ __align__(16) ushort_t PA[4][16 * PASTR];     // 9KB

    const int tid = threadIdx.x;
    const int wv = tid >> 6;
    const int lane = tid & 63;
    const int m16 = lane & 15;
    const int q = lane >> 4;

    {
        const uint4* gw = (const uint4*)pfrag;
        uint4* lw = (uint4*)WF;
        for (int i = tid; i < 2048; i += 256) lw[i] = gw[i];
    }
    __syncthreads();

    const int gid0 = (blockIdx.x * 4 + wv) * 16;
    ushort_t* At = &PA[wv][0];

    // gather 16 consecutive h rows -> bf16 A tile
    {
        const int row = lane >> 2, ch = lane & 3;
        const float4* hr = (const float4*)(h + (size_t)(gid0 + row) * HID + ch * 16);
        const float4 v0 = hr[0], v1 = hr[1], v2 = hr[2], v3 = hr[3];
        uint4 wA, wB;
        wA.x = pk2bf(v0.x, v0.y); wA.y = pk2bf(v0.z, v0.w);
        wA.z = pk2bf(v1.x, v1.y); wA.w = pk2bf(v1.z, v1.w);
        wB.x = pk2bf(v2.x, v2.y); wB.y = pk2bf(v2.z, v2.w);
        wB.z = pk2bf(v3.x, v3.y); wB.w = pk2bf(v3.z, v3.w);
        *(uint4*)&At[row * PASTR + ch * 16 + 0] = wA;
        *(uint4*)&At[row * PASTR + ch * 16 + 8] = wB;
    }

    const short8 a0 = *(const short8*)&At[m16 * PASTR +  0 + q * 8];
    const short8 a1 = *(const short8*)&At[m16 * PASTR + 32 + q * 8];

    // GEMM1: h(16x64) @ W1(64x256)
    floatx4 acc[16];
#pragma unroll
    for (int ct = 0; ct < 16; ++ct) {
        const short8 bf0 = *(const short8*)&WF[((size_t)(ct) * 64 + lane) * 8];
        const short8 bf1 = *(const short8*)&WF[((size_t)(16 + ct) * 64 + lane) * 8];
        floatx4 c = {0.f, 0.f, 0.f, 0.f};
        c = __builtin_amdgcn_mfma_f32_16x16x32_bf16(a0, bf0, c, 0, 0, 0);
        c = __builtin_amdgcn_mfma_f32_16x16x32_bf16(a1, bf1, c, 0, 0, 0);
        acc[ct] = c;
    }

    // GEMM2 (N=1): per-lane partial dot, then cross-lane reduce within 16-lane groups
    float b1v[16], w2v[16];
#pragma unroll
    for (int ct = 0; ct < 16; ++ct) {
        b1v[ct] = b1[ct * 16 + m16];
        w2v[ct] = w2[ct * 16 + m16];
    }
    float p[4] = {0.f, 0.f, 0.f, 0.f};
#pragma unroll
    for (int ct = 0; ct < 16; ++ct)
#pragma unroll
        for (int r = 0; r < 4; ++r)
            p[r] += gelu_f(acc[ct][r] + b1v[ct]) * w2v[ct];

#pragma unroll
    for (int r = 0; r < 4; ++r) {
        p[r] += __shfl_xor(p[r], 1);
        p[r] += __shfl_xor(p[r], 2);
        p[r] += __shfl_xor(p[r], 4);
        p[r] += __shfl_xor(p[r], 8);
    }
    if (m16 == 0) {
        const float b2s = b2[0];
#pragma unroll
        for (int r = 0; r < 4; ++r)
            out[gid0 + q * 4 + r] = p[r] + b2s;
    }
}

extern "C" void kernel_launch(void* const* d_in, const int* in_sizes, int n_in,
                              void* d_out, int out_size, void* d_ws, size_t ws_size,
                              hipStream_t stream)
{
    const float* x        = (const float*)d_in[0];
    const float* pos      = (const float*)d_in[1];
    const int*   ei       = (const int*)d_in[2];
    const float* lift_w1  = (const float*)d_in[3];
    const float* lift_b1  = (const float*)d_in[4];
    const float* lift_w2  = (const float*)d_in[5];
    const float* lift_b2  = (const float*)d_in[6];
    const float* kW1      = (const float*)d_in[7];
    const float* kb1      = (const float*)d_in[8];
    const float* kW2      = (const float*)d_in[9];
    const float* kb2      = (const float*)d_in[10];
    const float* proj_w1  = (const float*)d_in[11];
    const float* proj_b1  = (const float*)d_in[12];
    const float* proj_w2  = (const float*)d_in[13];
    const float* proj_b2  = (const float*)d_in[14];
    float* out = (float*)d_out;

    char* ws = (char*)d_ws;
    size_t off = 0;
    float* h0       = (float*)(ws + off); off += (size_t)BATCH * N_POINTS * HID * 4;
    float* h1       = (float*)(ws + off); off += (size_t)BATCH * N_POINTS * HID * 4;
    int* counts     = (int*)(ws + off);   off += (size_t)N_POINTS * 4;
    int* row_start  = (int*)(ws + off);   off += (size_t)(N_POINTS + 4) * 4;
    int* cursor     = (int*)(ws + off);   off += (size_t)N_POINTS * 4;   // dead after fill; wfrag aliases (128KB exactly)
    int* csr_src    = (int*)(ws + off);   off += (size_t)N_EDGES * 4;    // dead after layers; pfrag aliases
    int* csr_dst    = (int*)(ws + off);   off += (size_t)N_EDGES * 4;
    ushort_t* wfrag = (ushort_t*)cursor;  // FR_TOT * 1KB = 128KB == N_POINTS*4
    ushort_t* pfrag = (ushort_t*)csr_src; // 32KB <= 2MB

    hipMemsetAsync(counts, 0, N_POINTS * 4, stream);
    hipMemsetAsync(cursor, 0, N_POINTS * 4, stream);

    hist_kernel<<<N_EDGES / 256, 256, 0, stream>>>(ei, counts);
    scan_kernel<<<1, 1024, 0, stream>>>(counts, row_start);
    fill_kernel<<<N_EDGES / 256, 256, 0, stream>>>(ei, row_start, cursor, csr_src, csr_dst);
    wprep_kernel<<<(FR_TOT * 64) / 256, 256, 0, stream>>>(
        kW1, kb1, kW2, lift_w1, lift_b1, lift_w2, wfrag);

    lift_kernel<<<BATCH * N_POINTS / 64, 256, 0, stream>>>(x, pos, wfrag, lift_b2, h0);

    float* hin = h0;
    float* hout = h1;
    for (int l = 0; l < NLAYERS; ++l) {
        layer_kernel<<<dim3(N_POINTS / DSTS, BATCH), LK_THREADS, 0, stream>>>(
            hin, hout, pos, csr_src, csr_dst, row_start, counts,
            wfrag + (size_t)l * 20 * 64 * 8, kb2 + (size_t)l * HID);
        float* tmp = hin; hin = hout; hout = tmp;
    }

    // csr_src is dead now; build proj frags into its space, then proj
    wprep_proj_kernel<<<(32 * 64) / 256, 256, 0, stream>>>(proj_w1, pfrag);
    proj_kernel<<<BATCH * N_POINTS / 64, 256, 0, stream>>>(
        hin, pfrag, proj_b1, proj_w2, proj_b2, out);
}